// Round 2
// baseline (822.359 us; speedup 1.0000x reference)
//
#include <hip/hip_runtime.h>
#include <stdint.h>

#define DEV static __device__ __forceinline__

typedef __attribute__((ext_vector_type(8))) short bf16x8;
typedef __attribute__((ext_vector_type(4))) float f32x4;

constexpr int Bc = 8, Tc = 2048, Cc = 1024, Hc = 16, Dc = 64;

DEV ushort f2bf(float f) {
  union { float f; uint32_t u; } x{f};
  uint32_t r = (x.u + 0x7FFFu + ((x.u >> 16) & 1u)) >> 16;
  return (ushort)r;
}

DEV uint32_t cvt_pk_bf16(float a, float b) {
  uint32_t r;
  asm("v_cvt_pk_bf16_f32 %0, %1, %2" : "=v"(r) : "v"(a), "v"(b));
  return r;
}

DEV void gload16(const ushort* g, ushort* l) {
  __builtin_amdgcn_global_load_lds(
      (const __attribute__((address_space(1))) unsigned int*)g,
      (__attribute__((address_space(3))) unsigned int*)l, 16, 0, 0);
}

DEV f32x4 mfma16(bf16x8 a, bf16x8 b, f32x4 c) {
  return __builtin_amdgcn_mfma_f32_16x16x32_bf16(a, b, c, 0, 0, 0);
}

union B8 { bf16x8 v; uint4 u; };

// ---------------- converts ----------------
__global__ __launch_bounds__(256) void k_conv_x(const float* __restrict__ x, ushort* __restrict__ xb) {
  int i = blockIdx.x * 256 + threadIdx.x;
  float4 v = ((const float4*)x)[i];
  ushort4 o = make_ushort4(f2bf(v.x), f2bf(v.y), f2bf(v.z), f2bf(v.w));
  ((ushort4*)xb)[i] = o;
}

__global__ __launch_bounds__(256) void k_conv_wqkv(const float* __restrict__ wq, const float* __restrict__ wk,
                                                   const float* __restrict__ wv, ushort* __restrict__ wt) {
  int i = blockIdx.x * 256 + threadIdx.x;   // 0 .. 3072*1024-1
  int c = i & 1023;
  int n = i >> 10;
  int which = n >> 10;
  int rem = n & 1023;
  int h = rem >> 6, d = rem & 63;
  const float* src = which == 0 ? wq : (which == 1 ? wk : wv);
  float v = src[((size_t)h * 1024 + c) * 64 + d];
  // fold C^-0.5 = 1/32 AND log2(e) (for exp2-softmax) into wq
  if (which == 0) v *= 0.03125f * 1.44269504088896340736f;
  wt[i] = f2bf(v);
}

__global__ __launch_bounds__(256) void k_conv_wproj(const float* __restrict__ wp, ushort* __restrict__ wt) {
  int i = blockIdx.x * 256 + threadIdx.x;   // 0 .. 1024*1024-1
  int n = i >> 10, k = i & 1023;
  wt[i] = f2bf(wp[(size_t)k * 1024 + n]);
}

// ---------------- shared GEMM mainloop: 128x128 tile, BK=64, K=1024 ----------------
DEV void gemm_main(const ushort* __restrict__ A, const ushort* __restrict__ BT,
                   int m0, int n0, int tid, ushort* lds_a, ushort* lds_b,
                   f32x4 (&acc)[4][4]) {
  const int lane = tid & 63, wid = tid >> 6;
  const int lr = lane & 15, lg = lane >> 4;
  const int wm = wid >> 1, wn = wid & 1;
  for (int kt = 0; kt < 16; ++kt) {
#pragma unroll
    for (int r = 0; r < 4; ++r) {
      int flat = r * 256 + tid;      // 0..1023 chunks of 16B
      int row = flat >> 3, c8 = flat & 7;
      gload16(&A[(size_t)(m0 + row) * 1024 + kt * 64 + c8 * 8], &lds_a[flat * 8]);
      gload16(&BT[(size_t)(n0 + row) * 1024 + kt * 64 + c8 * 8], &lds_b[flat * 8]);
    }
    __syncthreads();
#pragma unroll
    for (int kc = 0; kc < 2; ++kc) {
      bf16x8 af[4], bfr[4];
#pragma unroll
      for (int mf = 0; mf < 4; ++mf)
        af[mf] = *(const bf16x8*)&lds_a[(wm * 64 + mf * 16 + lr) * 64 + kc * 32 + lg * 8];
#pragma unroll
      for (int nf = 0; nf < 4; ++nf)
        bfr[nf] = *(const bf16x8*)&lds_b[(wn * 64 + nf * 16 + lr) * 64 + kc * 32 + lg * 8];
#pragma unroll
      for (int mf = 0; mf < 4; ++mf)
#pragma unroll
        for (int nf = 0; nf < 4; ++nf)
          acc[mf][nf] = mfma16(af[mf], bfr[nf], acc[mf][nf]);
    }
    __syncthreads();
  }
}

// ---------------- QKV projection GEMM ----------------
__global__ __launch_bounds__(256) void k_gemm_qkv(const ushort* __restrict__ xb, const ushort* __restrict__ wt,
                                                  ushort* __restrict__ qws, ushort* __restrict__ kws,
                                                  ushort* __restrict__ vws) {
  __shared__ ushort lds_a[128 * 64];
  __shared__ ushort lds_b[128 * 64];
  const int tid = threadIdx.x;
  const int m0 = blockIdx.x * 128, n0 = blockIdx.y * 128;
  f32x4 acc[4][4];
  f32x4 z = {0.f, 0.f, 0.f, 0.f};
  for (int i = 0; i < 4; ++i) for (int j = 0; j < 4; ++j) acc[i][j] = z;
  gemm_main(xb, wt, m0, n0, tid, lds_a, lds_b, acc);
  const int lane = tid & 63, wid = tid >> 6;
  const int lr = lane & 15, lg = lane >> 4;
  const int wm = wid >> 1, wn = wid & 1;
#pragma unroll
  for (int mf = 0; mf < 4; ++mf)
#pragma unroll
    for (int nf = 0; nf < 4; ++nf)
#pragma unroll
      for (int r = 0; r < 4; ++r) {
        int m = m0 + wm * 64 + mf * 16 + lg * 4 + r;
        int n = n0 + wn * 64 + nf * 16 + lr;
        int which = n >> 10, rem = n & 1023;
        int h = rem >> 6, d = rem & 63;
        int b = m >> 11, t = m & 2047;
        ushort* dst = which == 0 ? qws : (which == 1 ? kws : vws);
        dst[((size_t)(b * Hc + h) * Tc + t) * 64 + d] = f2bf(acc[mf][nf][r]);
      }
}

// ---------------- V transpose: (B,H,T,D) -> (B,H,D,T) ----------------
__global__ __launch_bounds__(256) void k_vtrans(const ushort* __restrict__ v, ushort* __restrict__ vt) {
  __shared__ ushort lds[64][68];
  const int t0 = blockIdx.x * 64;
  const int bh = blockIdx.y;
  const int tid = threadIdx.x;
  const ushort* src = v + (size_t)bh * Tc * 64;
  ushort* dst = vt + (size_t)bh * 64 * Tc;
#pragma unroll
  for (int j = 0; j < 4; ++j) {
    int flat = j * 256 + tid;
    int row = flat >> 4, cg = flat & 15;
    ushort4 x = *(const ushort4*)&src[(size_t)(t0 + row) * 64 + cg * 4];
    lds[row][cg * 4 + 0] = x.x; lds[row][cg * 4 + 1] = x.y;
    lds[row][cg * 4 + 2] = x.z; lds[row][cg * 4 + 3] = x.w;
  }
  __syncthreads();
#pragma unroll
  for (int j = 0; j < 4; ++j) {
    int flat = j * 256 + tid;
    int d = flat >> 4, tg = flat & 15;
    ushort4 x = make_ushort4(lds[tg * 4 + 0][d], lds[tg * 4 + 1][d], lds[tg * 4 + 2][d], lds[tg * 4 + 3][d]);
    *(ushort4*)&dst[(size_t)d * Tc + t0 + tg * 4] = x;
  }
}

// ---------------- flash attention (causal), swapped-QK^T in-register softmax ----------------
// LDS: K and V^T tiles (64x64 bf16 each), double-buffered, XOR-swizzled, no P buffer.
DEV int swz(int row, int bcol) { return row * 128 + (bcol ^ ((row & 7) << 4)); }

__global__ __launch_bounds__(256) void k_attn(const ushort* __restrict__ qws, const ushort* __restrict__ kws,
                                              const ushort* __restrict__ vtws, ushort* __restrict__ att) {
  const int qi = gridDim.x - 1 - blockIdx.x;       // heavy blocks first
  const int q0 = qi * 128;
  const int bh = blockIdx.y;
  const int tid = threadIdx.x, lane = tid & 63, wid = tid >> 6;
  const int lr = lane & 15, lg = lane >> 4;

  __shared__ __align__(16) ushort lds_k[2 * 64 * 64];
  __shared__ __align__(16) ushort lds_v[2 * 64 * 64];

  const ushort* qbase = qws + (size_t)bh * Tc * 64;
  const ushort* kbase = kws + (size_t)bh * Tc * 64;
  const ushort* vtbase = vtws + (size_t)bh * 64 * Tc;

  const int qrow = q0 + wid * 32;
  const int qgmax = qrow + 31;

  // Q fragments (B-operand: lane (lg,lr) holds Q[qf*16+lr][kc*32+lg*8 ..+7])
  bf16x8 qa[2][2];
#pragma unroll
  for (int qf = 0; qf < 2; ++qf)
#pragma unroll
    for (int kc = 0; kc < 2; ++kc)
      qa[qf][kc] = *(const bf16x8*)&qbase[(size_t)(qrow + qf * 16 + lr) * 64 + kc * 32 + lg * 8];

  f32x4 o[2][4];
  float m_[2], l_[2];
  f32x4 z = {0.f, 0.f, 0.f, 0.f};
#pragma unroll
  for (int qf = 0; qf < 2; ++qf) {
#pragma unroll
    for (int df = 0; df < 4; ++df) o[qf][df] = z;
    m_[qf] = -1e30f; l_[qf] = 0.f;
  }

  const int ntiles = q0 / 64 + 2;

  // prologue: load tile 0 into regs
  int4 kreg[2], vreg[2];
#pragma unroll
  for (int r = 0; r < 2; ++r) {
    int flat = r * 256 + tid;
    int row = flat >> 3, c8 = flat & 7;
    kreg[r] = *(const int4*)&kbase[(size_t)row * 64 + c8 * 8];
    vreg[r] = *(const int4*)&vtbase[(size_t)row * Tc + c8 * 8];
  }

  for (int it = 0; it < ntiles; ++it) {
    ushort* ldsK = lds_k + (it & 1) * 4096;
    ushort* ldsV = lds_v + (it & 1) * 4096;
    // write current tile regs -> LDS (swizzled)
#pragma unroll
    for (int r = 0; r < 2; ++r) {
      int flat = r * 256 + tid;
      int row = flat >> 3, c8 = flat & 7;
      *(int4*)((char*)ldsK + swz(row, c8 * 16)) = kreg[r];
      *(int4*)((char*)ldsV + swz(row, c8 * 16)) = vreg[r];
    }
    // issue next tile loads (latency hides under this tile's compute)
    if (it + 1 < ntiles) {
      const int s0n = (it + 1) * 64;
#pragma unroll
      for (int r = 0; r < 2; ++r) {
        int flat = r * 256 + tid;
        int row = flat >> 3, c8 = flat & 7;
        kreg[r] = *(const int4*)&kbase[(size_t)(s0n + row) * 64 + c8 * 8];
        vreg[r] = *(const int4*)&vtbase[(size_t)row * Tc + s0n + c8 * 8];
      }
    }
    __syncthreads();

    const int s0 = it * 64;
    if (s0 > qgmax) continue;  // fully masked for this wave (still staged for others)

    // ---- QK^T swapped: S^T = K * Q^T. Lane (lg,lr): s[sf][qf][r] = S[s0+sf*16+lg*4+r][qrow+qf*16+lr]
    f32x4 s[4][2];
#pragma unroll
    for (int sf = 0; sf < 4; ++sf)
#pragma unroll
      for (int qf = 0; qf < 2; ++qf) s[sf][qf] = z;
#pragma unroll
    for (int kc = 0; kc < 2; ++kc) {
      bf16x8 kf[4];
#pragma unroll
      for (int sf = 0; sf < 4; ++sf)
        kf[sf] = *(const bf16x8*)((const char*)ldsK + swz(sf * 16 + lr, kc * 64 + lg * 16));
#pragma unroll
      for (int sf = 0; sf < 4; ++sf)
#pragma unroll
        for (int qf = 0; qf < 2; ++qf)
          s[sf][qf] = mfma16(kf[sf], qa[qf][kc], s[sf][qf]);
    }

    if (s0 + 63 > qrow) {  // causal masking needed in this tile
#pragma unroll
      for (int sf = 0; sf < 4; ++sf)
#pragma unroll
        for (int qf = 0; qf < 2; ++qf)
#pragma unroll
          for (int r = 0; r < 4; ++r) {
            int sg = s0 + sf * 16 + lg * 4 + r;
            int qg = qrow + qf * 16 + lr;
            if (sg > qg) s[sf][qf][r] = -1e30f;
          }
    }

    // ---- online softmax (base-2 units; log2e folded into wq)
    float sc[2];
#pragma unroll
    for (int qf = 0; qf < 2; ++qf) {
      // in-lane max tree over 16 values
      float t0_ = fmaxf(fmaxf(s[0][qf][0], s[0][qf][1]), fmaxf(s[0][qf][2], s[0][qf][3]));
      float t1_ = fmaxf(fmaxf(s[1][qf][0], s[1][qf][1]), fmaxf(s[1][qf][2], s[1][qf][3]));
      float t2_ = fmaxf(fmaxf(s[2][qf][0], s[2][qf][1]), fmaxf(s[2][qf][2], s[2][qf][3]));
      float t3_ = fmaxf(fmaxf(s[3][qf][0], s[3][qf][1]), fmaxf(s[3][qf][2], s[3][qf][3]));
      float t = fmaxf(fmaxf(t0_, t1_), fmaxf(t2_, t3_));
      t = fmaxf(t, __shfl_xor(t, 16));
      t = fmaxf(t, __shfl_xor(t, 32));
      float mnew = fmaxf(m_[qf], t);
      sc[qf] = exp2f(m_[qf] - mnew);
      m_[qf] = mnew;
      float sum = 0.f;
#pragma unroll
      for (int sf = 0; sf < 4; ++sf) {
#pragma unroll
        for (int r = 0; r < 4; ++r) {
          float p = exp2f(s[sf][qf][r] - mnew);
          s[sf][qf][r] = p;
          sum += p;
        }
      }
      sum += __shfl_xor(sum, 16);
      sum += __shfl_xor(sum, 32);
      l_[qf] = l_[qf] * sc[qf] + sum;
    }
    // rescale O (stats live at lane lr=q; O rows live at lg*4+r)
#pragma unroll
    for (int qf = 0; qf < 2; ++qf)
#pragma unroll
      for (int r = 0; r < 4; ++r) {
        float scR = __shfl(sc[qf], ((lane >> 4) << 2) + r);
#pragma unroll
        for (int df = 0; df < 4; ++df) o[qf][df][r] *= scR;
      }

    // ---- pack P to bf16 in-register (zero cross-lane movement)
    uint32_t pk_[4][2][2];
#pragma unroll
    for (int sf = 0; sf < 4; ++sf)
#pragma unroll
      for (int qf = 0; qf < 2; ++qf) {
        pk_[sf][qf][0] = cvt_pk_bf16(s[sf][qf][0], s[sf][qf][1]);
        pk_[sf][qf][1] = cvt_pk_bf16(s[sf][qf][2], s[sf][qf][3]);
      }

    // ---- PV with permuted k-slots: slot (lg,j) <-> s_local = 32kc + 16(j>>2) + 4lg + (j&3)
#pragma unroll
    for (int kc = 0; kc < 2; ++kc) {
      B8 vf[4];
#pragma unroll
      for (int df = 0; df < 4; ++df) {
        uint2 lo = *(const uint2*)((const char*)ldsV + swz(df * 16 + lr, kc * 64 + lg * 8));
        uint2 hi = *(const uint2*)((const char*)ldsV + swz(df * 16 + lr, kc * 64 + 32 + lg * 8));
        vf[df].u = make_uint4(lo.x, lo.y, hi.x, hi.y);
      }
      B8 pf[2];
#pragma unroll
      for (int qf = 0; qf < 2; ++qf)
        pf[qf].u = make_uint4(pk_[2 * kc][qf][0], pk_[2 * kc][qf][1],
                              pk_[2 * kc + 1][qf][0], pk_[2 * kc + 1][qf][1]);
#pragma unroll
      for (int qf = 0; qf < 2; ++qf)
#pragma unroll
        for (int df = 0; df < 4; ++df)
          o[qf][df] = mfma16(pf[qf].v, vf[df].v, o[qf][df]);
    }
  }

  const int b = bh >> 4, h = bh & 15;
#pragma unroll
  for (int qf = 0; qf < 2; ++qf)
#pragma unroll
    for (int r = 0; r < 4; ++r) {
      float lR = __shfl(l_[qf], ((lane >> 4) << 2) + r);
      float inv = 1.f / lR;
      int qg = qrow + qf * 16 + lg * 4 + r;
#pragma unroll
      for (int df = 0; df < 4; ++df) {
        int d = df * 16 + lr;
        att[(size_t)(b * Tc + qg) * 1024 + h * 64 + d] = f2bf(o[qf][df][r] * inv);
      }
    }
}

// ---------------- output projection GEMM (+bias, fp32 out) ----------------
__global__ __launch_bounds__(256) void k_gemm_proj(const ushort* __restrict__ attb, const ushort* __restrict__ wt,
                                                   const float* __restrict__ bias, float* __restrict__ out) {
  __shared__ ushort lds_a[128 * 64];
  __shared__ ushort lds_b[128 * 64];
  const int tid = threadIdx.x;
  const int m0 = blockIdx.x * 128, n0 = blockIdx.y * 128;
  f32x4 acc[4][4];
  f32x4 z = {0.f, 0.f, 0.f, 0.f};
  for (int i = 0; i < 4; ++i) for (int j = 0; j < 4; ++j) acc[i][j] = z;
  gemm_main(attb, wt, m0, n0, tid, lds_a, lds_b, acc);
  const int lane = tid & 63, wid = tid >> 6;
  const int lr = lane & 15, lg = lane >> 4;
  const int wm = wid >> 1, wn = wid & 1;
#pragma unroll
  for (int mf = 0; mf < 4; ++mf)
#pragma unroll
    for (int nf = 0; nf < 4; ++nf)
#pragma unroll
      for (int r = 0; r < 4; ++r) {
        int m = m0 + wm * 64 + mf * 16 + lg * 4 + r;
        int n = n0 + wn * 64 + nf * 16 + lr;
        out[(size_t)m * 1024 + n] = acc[mf][nf][r] + bias[n];
      }
}

extern "C" void kernel_launch(void* const* d_in, const int* in_sizes, int n_in,
                              void* d_out, int out_size, void* d_ws, size_t ws_size,
                              hipStream_t stream) {
  const float* x  = (const float*)d_in[0];
  const float* wq = (const float*)d_in[1];
  const float* wk = (const float*)d_in[2];
  const float* wv = (const float*)d_in[3];
  const float* wp = (const float*)d_in[4];
  const float* bp = (const float*)d_in[5];
  float* out = (float*)d_out;

  char* ws = (char*)d_ws;
  size_t off = 0;
  auto alloc = [&](size_t bytes) { char* p = ws + off; off += (bytes + 255) & ~255ull; return p; };
  ushort* xb   = (ushort*)alloc(16384ull * 1024 * 2);
  ushort* wqkv = (ushort*)alloc(3072ull * 1024 * 2);
  ushort* wpt  = (ushort*)alloc(1024ull * 1024 * 2);
  ushort* qws  = (ushort*)alloc(16384ull * 1024 * 2);
  ushort* kws  = (ushort*)alloc(16384ull * 1024 * 2);
  ushort* vws  = (ushort*)alloc(16384ull * 1024 * 2);
  ushort* vtws = (ushort*)alloc(16384ull * 1024 * 2);
  ushort* attb = xb;  // reuse: xb dead after k_gemm_qkv

  k_conv_x<<<16384, 256, 0, stream>>>(x, xb);
  k_conv_wqkv<<<12288, 256, 0, stream>>>(wq, wk, wv, wqkv);
  k_conv_wproj<<<4096, 256, 0, stream>>>(wp, wpt);
  k_gemm_qkv<<<dim3(128, 24), 256, 0, stream>>>(xb, wqkv, qws, kws, vws);
  k_vtrans<<<dim3(32, 128), 256, 0, stream>>>(vws, vtws);
  k_attn<<<dim3(16, 128), 256, 0, stream>>>(qws, kws, vtws, attb);
  k_gemm_proj<<<dim3(128, 8), 256, 0, stream>>>(attb, wpt, bp, out);
}

// Round 3
// 538.401 us; speedup vs baseline: 1.5274x; 1.5274x over previous
//
#include <hip/hip_runtime.h>
#include <stdint.h>

#define DEV static __device__ __forceinline__

typedef __attribute__((ext_vector_type(8))) short bf16x8;
typedef __attribute__((ext_vector_type(4))) float f32x4;

constexpr int Bc = 8, Tc = 2048, Cc = 1024, Hc = 16, Dc = 64;

DEV ushort f2bf(float f) {
  union { float f; uint32_t u; } x{f};
  uint32_t r = (x.u + 0x7FFFu + ((x.u >> 16) & 1u)) >> 16;
  return (ushort)r;
}

DEV uint32_t cvt_pk_bf16(float a, float b) {
  uint32_t r;
  asm("v_cvt_pk_bf16_f32 %0, %1, %2" : "=v"(r) : "v"(a), "v"(b));
  return r;
}

DEV void gload16(const ushort* g, ushort* l) {
  __builtin_amdgcn_global_load_lds(
      (const __attribute__((address_space(1))) unsigned int*)g,
      (__attribute__((address_space(3))) unsigned int*)l, 16, 0, 0);
}

DEV f32x4 mfma16(bf16x8 a, bf16x8 b, f32x4 c) {
  return __builtin_amdgcn_mfma_f32_16x16x32_bf16(a, b, c, 0, 0, 0);
}

union B8 { bf16x8 v; uint4 u; };

// ---------------- converts ----------------
__global__ __launch_bounds__(256) void k_conv_x(const float* __restrict__ x, ushort* __restrict__ xb) {
  int i = blockIdx.x * 256 + threadIdx.x;
  float4 v = ((const float4*)x)[i];
  ushort4 o = make_ushort4(f2bf(v.x), f2bf(v.y), f2bf(v.z), f2bf(v.w));
  ((ushort4*)xb)[i] = o;
}

__global__ __launch_bounds__(256) void k_conv_wqkv(const float* __restrict__ wq, const float* __restrict__ wk,
                                                   const float* __restrict__ wv, ushort* __restrict__ wt) {
  int i = blockIdx.x * 256 + threadIdx.x;   // 0 .. 3072*1024-1
  int c = i & 1023;
  int n = i >> 10;
  int which = n >> 10;
  int rem = n & 1023;
  int h = rem >> 6, d = rem & 63;
  const float* src = which == 0 ? wq : (which == 1 ? wk : wv);
  float v = src[((size_t)h * 1024 + c) * 64 + d];
  // fold C^-0.5 = 1/32 AND log2(e) (for exp2-softmax) into wq
  if (which == 0) v *= 0.03125f * 1.44269504088896340736f;
  wt[i] = f2bf(v);
}

__global__ __launch_bounds__(256) void k_conv_wproj(const float* __restrict__ wp, ushort* __restrict__ wt) {
  int i = blockIdx.x * 256 + threadIdx.x;   // 0 .. 1024*1024-1
  int n = i >> 10, k = i & 1023;
  wt[i] = f2bf(wp[(size_t)k * 1024 + n]);
}

// ---------------- shared GEMM mainloop: 128x128 tile, BK=64, K=1024 ----------------
DEV void gemm_main(const ushort* __restrict__ A, const ushort* __restrict__ BT,
                   int m0, int n0, int tid, ushort* lds_a, ushort* lds_b,
                   f32x4 (&acc)[4][4]) {
  const int lane = tid & 63, wid = tid >> 6;
  const int lr = lane & 15, lg = lane >> 4;
  const int wm = wid >> 1, wn = wid & 1;
  for (int kt = 0; kt < 16; ++kt) {
#pragma unroll
    for (int r = 0; r < 4; ++r) {
      int flat = r * 256 + tid;      // 0..1023 chunks of 16B
      int row = flat >> 3, c8 = flat & 7;
      gload16(&A[(size_t)(m0 + row) * 1024 + kt * 64 + c8 * 8], &lds_a[flat * 8]);
      gload16(&BT[(size_t)(n0 + row) * 1024 + kt * 64 + c8 * 8], &lds_b[flat * 8]);
    }
    __syncthreads();
#pragma unroll
    for (int kc = 0; kc < 2; ++kc) {
      bf16x8 af[4], bfr[4];
#pragma unroll
      for (int mf = 0; mf < 4; ++mf)
        af[mf] = *(const bf16x8*)&lds_a[(wm * 64 + mf * 16 + lr) * 64 + kc * 32 + lg * 8];
#pragma unroll
      for (int nf = 0; nf < 4; ++nf)
        bfr[nf] = *(const bf16x8*)&lds_b[(wn * 64 + nf * 16 + lr) * 64 + kc * 32 + lg * 8];
      __builtin_amdgcn_s_setprio(1);
#pragma unroll
      for (int mf = 0; mf < 4; ++mf)
#pragma unroll
        for (int nf = 0; nf < 4; ++nf)
          acc[mf][nf] = mfma16(af[mf], bfr[nf], acc[mf][nf]);
      __builtin_amdgcn_s_setprio(0);
    }
    __syncthreads();
  }
}

// ---------------- QKV projection GEMM ----------------
__global__ __launch_bounds__(256) void k_gemm_qkv(const ushort* __restrict__ xb, const ushort* __restrict__ wt,
                                                  ushort* __restrict__ qws, ushort* __restrict__ kws,
                                                  ushort* __restrict__ vws) {
  __shared__ ushort lds_a[128 * 64];
  __shared__ ushort lds_b[128 * 64];
  const int tid = threadIdx.x;
  const int m0 = blockIdx.y * 128, n0 = blockIdx.x * 128;
  f32x4 acc[4][4];
  f32x4 z = {0.f, 0.f, 0.f, 0.f};
  for (int i = 0; i < 4; ++i) for (int j = 0; j < 4; ++j) acc[i][j] = z;
  gemm_main(xb, wt, m0, n0, tid, lds_a, lds_b, acc);
  const int lane = tid & 63, wid = tid >> 6;
  const int lr = lane & 15, lg = lane >> 4;
  const int wm = wid >> 1, wn = wid & 1;
#pragma unroll
  for (int mf = 0; mf < 4; ++mf)
#pragma unroll
    for (int nf = 0; nf < 4; ++nf)
#pragma unroll
      for (int r = 0; r < 4; ++r) {
        int m = m0 + wm * 64 + mf * 16 + lg * 4 + r;
        int n = n0 + wn * 64 + nf * 16 + lr;
        int which = n >> 10, rem = n & 1023;
        int h = rem >> 6, d = rem & 63;
        int b = m >> 11, t = m & 2047;
        ushort* dst = which == 0 ? qws : (which == 1 ? kws : vws);
        dst[((size_t)(b * Hc + h) * Tc + t) * 64 + d] = f2bf(acc[mf][nf][r]);
      }
}

// ---------------- V transpose: (B,H,T,D) -> (B,H,D,T) ----------------
__global__ __launch_bounds__(256) void k_vtrans(const ushort* __restrict__ v, ushort* __restrict__ vt) {
  __shared__ ushort lds[64][68];
  const int t0 = blockIdx.x * 64;
  const int bh = blockIdx.y;
  const int tid = threadIdx.x;
  const ushort* src = v + (size_t)bh * Tc * 64;
  ushort* dst = vt + (size_t)bh * 64 * Tc;
#pragma unroll
  for (int j = 0; j < 4; ++j) {
    int flat = j * 256 + tid;
    int row = flat >> 4, cg = flat & 15;
    ushort4 x = *(const ushort4*)&src[(size_t)(t0 + row) * 64 + cg * 4];
    lds[row][cg * 4 + 0] = x.x; lds[row][cg * 4 + 1] = x.y;
    lds[row][cg * 4 + 2] = x.z; lds[row][cg * 4 + 3] = x.w;
  }
  __syncthreads();
#pragma unroll
  for (int j = 0; j < 4; ++j) {
    int flat = j * 256 + tid;
    int d = flat >> 4, tg = flat & 15;
    ushort4 x = make_ushort4(lds[tg * 4 + 0][d], lds[tg * 4 + 1][d], lds[tg * 4 + 2][d], lds[tg * 4 + 3][d]);
    *(ushort4*)&dst[(size_t)d * Tc + t0 + tg * 4] = x;
  }
}

// ---------------- flash attention (causal) ----------------
// Paired q-blocks (qi, 15-qi): every block = exactly 36 KV tiles -> perfect balance.
// XCD-locality decode: 16 consecutive bh per XCD -> KV stays L2-resident.
// Swapped QK^T, in-register softmax/P, XOR-swizzled double-buffered LDS, 1-tile prefetch.
DEV int swz(int row, int bcol) { return row * 128 + (bcol ^ ((row & 7) << 4)); }

__global__ __launch_bounds__(256) void k_attn(const ushort* __restrict__ qws, const ushort* __restrict__ kws,
                                              const ushort* __restrict__ vtws, ushort* __restrict__ att) {
  const int id = blockIdx.x;
  const int xcd = id & 7, slot = id >> 3;
  const int bh = (xcd << 4) + (slot >> 3);   // 16 bh per XCD, same-bh blocks adjacent
  const int qi = slot & 7;                    // 0..7
  const int tid = threadIdx.x, lane = tid & 63, wid = tid >> 6;
  const int lr = lane & 15, lg = lane >> 4;

  __shared__ __align__(16) ushort lds_k[2 * 64 * 64];
  __shared__ __align__(16) ushort lds_v[2 * 64 * 64];

  const ushort* qbase = qws + (size_t)bh * Tc * 64;
  const ushort* kbase = kws + (size_t)bh * Tc * 64;
  const ushort* vtbase = vtws + (size_t)bh * 64 * Tc;
  const int b = bh >> 4, h = bh & 15;
  const f32x4 z = {0.f, 0.f, 0.f, 0.f};

  for (int pass = 0; pass < 2; ++pass) {
    const int qb = pass == 0 ? qi : 15 - qi;
    const int q0 = qb * 128;
    const int ntiles = 2 * qb + 2;
    const int qrow = q0 + wid * 32;
    const int qgmax = qrow + 31;

    // Q fragments (B-operand: lane (lg,lr) holds Q[qf*16+lr][kc*32+lg*8 ..+7])
    bf16x8 qa[2][2];
#pragma unroll
    for (int qf = 0; qf < 2; ++qf)
#pragma unroll
      for (int kc = 0; kc < 2; ++kc)
        qa[qf][kc] = *(const bf16x8*)&qbase[(size_t)(qrow + qf * 16 + lr) * 64 + kc * 32 + lg * 8];

    f32x4 o[2][4];
    float m_[2], l_[2];
#pragma unroll
    for (int qf = 0; qf < 2; ++qf) {
#pragma unroll
      for (int df = 0; df < 4; ++df) o[qf][df] = z;
      m_[qf] = -1e30f; l_[qf] = 0.f;
    }

    __syncthreads();  // protect LDS buffers across pass boundary

    // prologue: load tile 0 into regs
    int4 kreg[2], vreg[2];
#pragma unroll
    for (int r = 0; r < 2; ++r) {
      int flat = r * 256 + tid;
      int row = flat >> 3, c8 = flat & 7;
      kreg[r] = *(const int4*)&kbase[(size_t)row * 64 + c8 * 8];
      vreg[r] = *(const int4*)&vtbase[(size_t)row * Tc + c8 * 8];
    }

    for (int it = 0; it < ntiles; ++it) {
      ushort* ldsK = lds_k + (it & 1) * 4096;
      ushort* ldsV = lds_v + (it & 1) * 4096;
#pragma unroll
      for (int r = 0; r < 2; ++r) {
        int flat = r * 256 + tid;
        int row = flat >> 3, c8 = flat & 7;
        *(int4*)((char*)ldsK + swz(row, c8 * 16)) = kreg[r];
        *(int4*)((char*)ldsV + swz(row, c8 * 16)) = vreg[r];
      }
      if (it + 1 < ntiles) {  // prefetch next tile (hides under this tile's compute)
        const int s0n = (it + 1) * 64;
#pragma unroll
        for (int r = 0; r < 2; ++r) {
          int flat = r * 256 + tid;
          int row = flat >> 3, c8 = flat & 7;
          kreg[r] = *(const int4*)&kbase[(size_t)(s0n + row) * 64 + c8 * 8];
          vreg[r] = *(const int4*)&vtbase[(size_t)row * Tc + s0n + c8 * 8];
        }
      }
      __syncthreads();

      const int s0 = it * 64;
      if (s0 > qgmax) continue;  // fully masked for this wave (still staged for others)

      // ---- QK^T swapped: lane (lg,lr): s[sf][qf][r] = S[s0+sf*16+lg*4+r][qrow+qf*16+lr]
      f32x4 s[4][2];
#pragma unroll
      for (int sf = 0; sf < 4; ++sf)
#pragma unroll
        for (int qf = 0; qf < 2; ++qf) s[sf][qf] = z;
#pragma unroll
      for (int kc = 0; kc < 2; ++kc) {
        bf16x8 kf[4];
#pragma unroll
        for (int sf = 0; sf < 4; ++sf)
          kf[sf] = *(const bf16x8*)((const char*)ldsK + swz(sf * 16 + lr, kc * 64 + lg * 16));
        __builtin_amdgcn_s_setprio(1);
#pragma unroll
        for (int sf = 0; sf < 4; ++sf)
#pragma unroll
          for (int qf = 0; qf < 2; ++qf)
            s[sf][qf] = mfma16(kf[sf], qa[qf][kc], s[sf][qf]);
        __builtin_amdgcn_s_setprio(0);
      }

      if (s0 + 63 > qrow) {  // causal masking (diagonal tiles only)
#pragma unroll
        for (int sf = 0; sf < 4; ++sf)
#pragma unroll
          for (int qf = 0; qf < 2; ++qf)
#pragma unroll
            for (int r = 0; r < 4; ++r) {
              int sg = s0 + sf * 16 + lg * 4 + r;
              int qg = qrow + qf * 16 + lr;
              if (sg > qg) s[sf][qf][r] = -1e30f;
            }
      }

      // ---- online softmax (base-2 units), defer-max rescale (T13)
      float sc[2];
      bool defer[2];
#pragma unroll
      for (int qf = 0; qf < 2; ++qf) {
        float t0_ = fmaxf(fmaxf(s[0][qf][0], s[0][qf][1]), fmaxf(s[0][qf][2], s[0][qf][3]));
        float t1_ = fmaxf(fmaxf(s[1][qf][0], s[1][qf][1]), fmaxf(s[1][qf][2], s[1][qf][3]));
        float t2_ = fmaxf(fmaxf(s[2][qf][0], s[2][qf][1]), fmaxf(s[2][qf][2], s[2][qf][3]));
        float t3_ = fmaxf(fmaxf(s[3][qf][0], s[3][qf][1]), fmaxf(s[3][qf][2], s[3][qf][3]));
        float t = fmaxf(fmaxf(t0_, t1_), fmaxf(t2_, t3_));
        t = fmaxf(t, __shfl_xor(t, 16));
        t = fmaxf(t, __shfl_xor(t, 32));
        defer[qf] = __all(t <= m_[qf] + 11.54f) != 0;  // ~e^8 headroom
        float mnew = defer[qf] ? m_[qf] : fmaxf(m_[qf], t);
        sc[qf] = defer[qf] ? 1.f : exp2f(m_[qf] - mnew);
        m_[qf] = mnew;
        float sum = 0.f;
#pragma unroll
        for (int sf = 0; sf < 4; ++sf)
#pragma unroll
          for (int r = 0; r < 4; ++r) {
            float p = exp2f(s[sf][qf][r] - mnew);
            s[sf][qf][r] = p;
            sum += p;
          }
        sum += __shfl_xor(sum, 16);
        sum += __shfl_xor(sum, 32);
        l_[qf] = l_[qf] * sc[qf] + sum;
      }
#pragma unroll
      for (int qf = 0; qf < 2; ++qf)
        if (!defer[qf]) {
#pragma unroll
          for (int r = 0; r < 4; ++r) {
            float scR = __shfl(sc[qf], ((lane >> 4) << 2) + r);
#pragma unroll
            for (int df = 0; df < 4; ++df) o[qf][df][r] *= scR;
          }
        }

      // ---- pack P to bf16 in-register
      uint32_t pk_[4][2][2];
#pragma unroll
      for (int sf = 0; sf < 4; ++sf)
#pragma unroll
        for (int qf = 0; qf < 2; ++qf) {
          pk_[sf][qf][0] = cvt_pk_bf16(s[sf][qf][0], s[sf][qf][1]);
          pk_[sf][qf][1] = cvt_pk_bf16(s[sf][qf][2], s[sf][qf][3]);
        }

      // ---- PV with permuted k-slots
#pragma unroll
      for (int kc = 0; kc < 2; ++kc) {
        B8 vf[4];
#pragma unroll
        for (int df = 0; df < 4; ++df) {
          uint2 lo = *(const uint2*)((const char*)ldsV + swz(df * 16 + lr, kc * 64 + lg * 8));
          uint2 hi = *(const uint2*)((const char*)ldsV + swz(df * 16 + lr, kc * 64 + 32 + lg * 8));
          vf[df].u = make_uint4(lo.x, lo.y, hi.x, hi.y);
        }
        B8 pf[2];
#pragma unroll
        for (int qf = 0; qf < 2; ++qf)
          pf[qf].u = make_uint4(pk_[2 * kc][qf][0], pk_[2 * kc][qf][1],
                                pk_[2 * kc + 1][qf][0], pk_[2 * kc + 1][qf][1]);
        __builtin_amdgcn_s_setprio(1);
#pragma unroll
        for (int qf = 0; qf < 2; ++qf)
#pragma unroll
          for (int df = 0; df < 4; ++df)
            o[qf][df] = mfma16(pf[qf].v, vf[df].v, o[qf][df]);
        __builtin_amdgcn_s_setprio(0);
      }
    }

    // epilogue: store this pass's O
#pragma unroll
    for (int qf = 0; qf < 2; ++qf)
#pragma unroll
      for (int r = 0; r < 4; ++r) {
        float lR = __shfl(l_[qf], ((lane >> 4) << 2) + r);
        float inv = 1.f / lR;
        int qg = qrow + qf * 16 + lg * 4 + r;
#pragma unroll
        for (int df = 0; df < 4; ++df) {
          int d = df * 16 + lr;
          att[(size_t)(b * Tc + qg) * 1024 + h * 64 + d] = f2bf(o[qf][df][r] * inv);
        }
      }
  }
}

// ---------------- output projection GEMM (+bias, fp32 out) ----------------
__global__ __launch_bounds__(256) void k_gemm_proj(const ushort* __restrict__ attb, const ushort* __restrict__ wt,
                                                   const float* __restrict__ bias, float* __restrict__ out) {
  __shared__ ushort lds_a[128 * 64];
  __shared__ ushort lds_b[128 * 64];
  const int tid = threadIdx.x;
  const int m0 = blockIdx.y * 128, n0 = blockIdx.x * 128;
  f32x4 acc[4][4];
  f32x4 z = {0.f, 0.f, 0.f, 0.f};
  for (int i = 0; i < 4; ++i) for (int j = 0; j < 4; ++j) acc[i][j] = z;
  gemm_main(attb, wt, m0, n0, tid, lds_a, lds_b, acc);
  const int lane = tid & 63, wid = tid >> 6;
  const int lr = lane & 15, lg = lane >> 4;
  const int wm = wid >> 1, wn = wid & 1;
#pragma unroll
  for (int mf = 0; mf < 4; ++mf)
#pragma unroll
    for (int nf = 0; nf < 4; ++nf)
#pragma unroll
      for (int r = 0; r < 4; ++r) {
        int m = m0 + wm * 64 + mf * 16 + lg * 4 + r;
        int n = n0 + wn * 64 + nf * 16 + lr;
        out[(size_t)m * 1024 + n] = acc[mf][nf][r] + bias[n];
      }
}

extern "C" void kernel_launch(void* const* d_in, const int* in_sizes, int n_in,
                              void* d_out, int out_size, void* d_ws, size_t ws_size,
                              hipStream_t stream) {
  const float* x  = (const float*)d_in[0];
  const float* wq = (const float*)d_in[1];
  const float* wk = (const float*)d_in[2];
  const float* wv = (const float*)d_in[3];
  const float* wp = (const float*)d_in[4];
  const float* bp = (const float*)d_in[5];
  float* out = (float*)d_out;

  char* ws = (char*)d_ws;
  size_t off = 0;
  auto alloc = [&](size_t bytes) { char* p = ws + off; off += (bytes + 255) & ~255ull; return p; };
  ushort* xb   = (ushort*)alloc(16384ull * 1024 * 2);
  ushort* wqkv = (ushort*)alloc(3072ull * 1024 * 2);
  ushort* wpt  = (ushort*)alloc(1024ull * 1024 * 2);
  ushort* qws  = (ushort*)alloc(16384ull * 1024 * 2);
  ushort* kws  = (ushort*)alloc(16384ull * 1024 * 2);
  ushort* vws  = (ushort*)alloc(16384ull * 1024 * 2);
  ushort* vtws = (ushort*)alloc(16384ull * 1024 * 2);
  ushort* attb = xb;  // reuse: xb dead after k_gemm_qkv

  k_conv_x<<<16384, 256, 0, stream>>>(x, xb);
  k_conv_wqkv<<<12288, 256, 0, stream>>>(wq, wk, wv, wqkv);
  k_conv_wproj<<<4096, 256, 0, stream>>>(wp, wpt);
  k_gemm_qkv<<<dim3(24, 128), 256, 0, stream>>>(xb, wqkv, qws, kws, vws);
  k_vtrans<<<dim3(32, 128), 256, 0, stream>>>(vws, vtws);
  k_attn<<<1024, 256, 0, stream>>>(qws, kws, vtws, attb);
  k_gemm_proj<<<dim3(8, 128), 256, 0, stream>>>(attb, wpt, bp, out);
}